// Round 1
// baseline (1018.159 us; speedup 1.0000x reference)
//
#include <hip/hip_runtime.h>
#include <hip/hip_bf16.h>

// ---------------------------------------------------------------------------
// S4D stack: encoder GEMM -> 4x[SSM scan conv + GELU -> GLU GEMM + LN] -> dec
// All fp32. Layout (B*L, H) row-major everywhere (coalesced per-position).
// Conv implemented as chunked linear recurrence (3 passes), not FFT.
// Requires ~104 MB of d_ws.
// ---------------------------------------------------------------------------

constexpr int B_ = 4, L_ = 8192, DIN = 64, H_ = 256, N2_ = 32, NL_ = 4, DOUT = 10;
constexpr int LC = 64, CHK = L_ / LC;     // chunk len 64, 128 chunks
constexpr int M_ = B_ * L_;               // 32768 positions

// ws layout in floats
constexpr size_t SZ_H    = (size_t)M_ * H_;            // 8.39M
constexpr size_t OFF_H   = 0;
constexpr size_t OFF_Y   = OFF_H + SZ_H;
constexpr size_t SZ_ST   = (size_t)B_ * CHK * H_ * N2_ * 2;
constexpr size_t OFF_ST  = OFF_Y + SZ_H;
constexpr size_t SZ_P    = (size_t)NL_ * H_ * N2_ * 2;
constexpr size_t OFF_W   = OFF_ST + SZ_ST;
constexpr size_t OFF_CT  = OFF_W + SZ_P;
constexpr size_t OFF_WLC = OFF_CT + SZ_P;
constexpr size_t OFF_EWT = OFF_WLC + SZ_P;
constexpr size_t SZ_EWT  = (size_t)DIN * H_;
constexpr size_t OFF_WOT = OFF_EWT + SZ_EWT;
constexpr size_t SZ_WOT  = (size_t)NL_ * H_ * 2 * H_;

// ---------------------------------------------------------------------------
// per-layer SSM parameters: w = exp(dt*A), Ct2 = 2*C*(w-1)/A, wLc = w^LC
__global__ __launch_bounds__(256) void k_params(
    const float* __restrict__ log_dt, const float* __restrict__ log_A_re,
    const float* __restrict__ A_im, const float* __restrict__ C_re,
    const float* __restrict__ C_im, float* __restrict__ ws)
{
    int idx = blockIdx.x * 256 + threadIdx.x;     // over NL*H*N2
    if (idx >= NL_ * H_ * N2_) return;
    int i  = idx / (H_ * N2_);
    int hh = (idx / N2_) % H_;
    float dt  = expf(log_dt[i * H_ + hh]);
    float Are = -expf(log_A_re[idx]);
    float Aim = A_im[idx];
    float zre = dt * Are, zim = dt * Aim;
    float er  = expf(zre);
    float wre = er * cosf(zim), wim = er * sinf(zim);
    // q = (w - 1) / A
    float d   = Are * Are + Aim * Aim;
    float nre = wre - 1.f, nim = wim;
    float qre = (nre * Are + nim * Aim) / d;
    float qim = (nim * Are - nre * Aim) / d;
    float cr = C_re[idx], ci = C_im[idx];
    float ctre = cr * qre - ci * qim;
    float ctim = cr * qim + ci * qre;
    float er2 = expf(zre * (float)LC);
    float wlre = er2 * cosf(zim * (float)LC);
    float wlim = er2 * sinf(zim * (float)LC);
    ((float2*)(ws + OFF_W))[idx]   = make_float2(wre, wim);
    ((float2*)(ws + OFF_CT))[idx]  = make_float2(2.f * ctre, 2.f * ctim);
    ((float2*)(ws + OFF_WLC))[idx] = make_float2(wlre, wlim);
}

// ---------------------------------------------------------------------------
__global__ __launch_bounds__(256) void k_transpose(const float* __restrict__ src,
    float* __restrict__ dst, int R, int Cc)   // src R x Cc -> dst Cc x R
{
    __shared__ float t[32][33];
    int x = blockIdx.x * 32 + threadIdx.x;    // col
    #pragma unroll
    for (int i = 0; i < 4; i++) {
        int yy = blockIdx.y * 32 + threadIdx.y + i * 8;
        if (x < Cc && yy < R) t[threadIdx.y + i * 8][threadIdx.x] = src[(size_t)yy * Cc + x];
    }
    __syncthreads();
    int xo = blockIdx.y * 32 + threadIdx.x;   // original row
    #pragma unroll
    for (int i = 0; i < 4; i++) {
        int yo = blockIdx.x * 32 + threadIdx.y + i * 8;  // original col
        if (xo < R && yo < Cc) dst[(size_t)yo * R + xo] = t[threadIdx.x][threadIdx.y + i * 8];
    }
}

// ---------------------------------------------------------------------------
// encoder: h[M,256] = x[M,64] @ encWT[64,256] + enc_b
__global__ __launch_bounds__(256) void k_encoder(const float* __restrict__ x,
    const float* __restrict__ encWT, const float* __restrict__ enc_b,
    float* __restrict__ h)
{
    __shared__ float As[DIN][36];     // k-major A tile (32 pos)
    __shared__ float Bs[32][256];
    int m0 = blockIdx.x * 32;
    int tid = threadIdx.x;
    const float4* x4 = (const float4*)x;
    #pragma unroll
    for (int q = 0; q < 2; q++) {
        int f = tid * 2 + q;          // 512 float4 of the 32x64 tile
        int row = f >> 4, kq = f & 15;
        float4 v = x4[(size_t)(m0 + row) * 16 + kq];
        As[kq * 4 + 0][row] = v.x; As[kq * 4 + 1][row] = v.y;
        As[kq * 4 + 2][row] = v.z; As[kq * 4 + 3][row] = v.w;
    }
    int tx = tid & 31, ty = tid >> 5;
    float acc[4][8];
    #pragma unroll
    for (int p = 0; p < 4; p++)
        #pragma unroll
        for (int j = 0; j < 8; j++) acc[p][j] = 0.f;
    const float4* w4 = (const float4*)encWT;
    for (int ks = 0; ks < 2; ks++) {
        __syncthreads();
        #pragma unroll
        for (int it = 0; it < 8; it++) {
            int q = it * 256 + tid;
            ((float4*)Bs)[q] = w4[ks * 2048 + q];
        }
        __syncthreads();
        #pragma unroll 8
        for (int kk = 0; kk < 32; kk++) {
            int k = ks * 32 + kk;
            float4 a  = *(const float4*)&As[k][ty * 4];
            float4 b0 = *(const float4*)&Bs[kk][tx * 4];
            float4 b1 = *(const float4*)&Bs[kk][128 + tx * 4];
            float av[4] = {a.x, a.y, a.z, a.w};
            float bv[8] = {b0.x, b0.y, b0.z, b0.w, b1.x, b1.y, b1.z, b1.w};
            #pragma unroll
            for (int p = 0; p < 4; p++)
                #pragma unroll
                for (int j = 0; j < 8; j++)
                    acc[p][j] = fmaf(av[p], bv[j], acc[p][j]);
        }
    }
    float4 eb0 = *(const float4*)&enc_b[tx * 4];
    float4 eb1 = *(const float4*)&enc_b[128 + tx * 4];
    float ebv[8] = {eb0.x, eb0.y, eb0.z, eb0.w, eb1.x, eb1.y, eb1.z, eb1.w};
    float4* h4 = (float4*)h;
    #pragma unroll
    for (int p = 0; p < 4; p++) {
        size_t pos = m0 + ty * 4 + p;
        float4 o0 = make_float4(acc[p][0] + ebv[0], acc[p][1] + ebv[1],
                                acc[p][2] + ebv[2], acc[p][3] + ebv[3]);
        float4 o1 = make_float4(acc[p][4] + ebv[4], acc[p][5] + ebv[5],
                                acc[p][6] + ebv[6], acc[p][7] + ebv[7]);
        h4[pos * 64 + tx]      = o0;
        h4[pos * 64 + 32 + tx] = o1;
    }
}

// ---------------------------------------------------------------------------
// pass1: per-chunk local final state (zero init). thread = (b,c,h,n)
__global__ __launch_bounds__(256) void k_chunkstate(const float* __restrict__ hin,
    const float* __restrict__ ws, int layer, float* __restrict__ st)
{
    int bid = blockIdx.x;                 // B*CHK*32 blocks
    int hg = bid & 31;
    int c  = (bid >> 5) & (CHK - 1);
    int b  = bid >> 12;
    int n  = threadIdx.x & 31;
    int hh = hg * 8 + (threadIdx.x >> 5);
    float2 w = ((const float2*)(ws + OFF_W))[(size_t)layer * H_ * N2_ + hh * N2_ + n];
    float sre = 0.f, sim = 0.f;
    const float* xp = hin + ((size_t)b * L_ + c * LC) * H_ + hh;
    #pragma unroll 4
    for (int t = 0; t < LC; t++) {
        float xv = xp[t * H_];
        float tre = fmaf(w.x, sre, xv);
        tre = fmaf(-w.y, sim, tre);
        float tim = fmaf(w.x, sim, w.y * sre);
        sre = tre; sim = tim;
    }
    ((float2*)st)[((size_t)(b * CHK + c) * H_ + hh) * N2_ + n] = make_float2(sre, sim);
}

// ---------------------------------------------------------------------------
// pass2: cross-chunk scan; st[c] becomes the INCOMING state of chunk c (in-place)
__global__ __launch_bounds__(256) void k_scan(const float* __restrict__ ws, int layer,
    float* __restrict__ st)
{
    int gid = blockIdx.x * 256 + threadIdx.x;   // B*H*N2 = 32768
    int b = gid >> 13;
    int r = gid & 8191;
    float2 wl = ((const float2*)(ws + OFF_WLC))[(size_t)layer * H_ * N2_ + r];
    float2* stp = (float2*)st;
    float cre = 0.f, cim = 0.f;
    for (int c = 0; c < CHK; c++) {
        size_t idx = (size_t)(b * CHK + c) * H_ * N2_ + r;
        float2 sl = stp[idx];
        stp[idx] = make_float2(cre, cim);
        float tre = fmaf(wl.x, cre, sl.x);
        tre = fmaf(-wl.y, cim, tre);
        float tim = fmaf(wl.x, cim, sl.y);
        tim = fmaf(wl.y, cre, tim);
        cre = tre; cim = tim;
    }
}

// ---------------------------------------------------------------------------
// pass3: replay with carries; y = gelu(conv + D*u). thread = channel (32 states in regs)
#define STEP(n, A) { \
    float tre = fmaf(wre[n], sre[n], xv); \
    tre = fmaf(-wim[n], sim[n], tre); \
    float tim = fmaf(wre[n], sim[n], wim[n] * sre[n]); \
    sre[n] = tre; sim[n] = tim; \
    A = fmaf(cre_[n], tre, A); \
    A = fmaf(-cim_[n], tim, A); }

__global__ __launch_bounds__(256) void k_conv(const float* __restrict__ hin,
    const float* __restrict__ ws, int layer, const float* __restrict__ Dp,
    const float* __restrict__ st, float* __restrict__ yout)
{
    int c = blockIdx.x & (CHK - 1);
    int b = blockIdx.x >> 7;
    int hh = threadIdx.x;
    float wre[N2_], wim[N2_], cre_[N2_], cim_[N2_], sre[N2_], sim[N2_];
    const float4* w4 = (const float4*)(ws + OFF_W  + ((size_t)layer * H_ * N2_ + hh * N2_) * 2);
    const float4* c4 = (const float4*)(ws + OFF_CT + ((size_t)layer * H_ * N2_ + hh * N2_) * 2);
    const float4* s4 = (const float4*)(st + ((size_t)(b * CHK + c) * H_ + hh) * N2_ * 2);
    #pragma unroll
    for (int j = 0; j < 16; j++) {
        float4 v = w4[j]; wre[2*j] = v.x; wim[2*j] = v.y; wre[2*j+1] = v.z; wim[2*j+1] = v.w;
        float4 u = c4[j]; cre_[2*j] = u.x; cim_[2*j] = u.y; cre_[2*j+1] = u.z; cim_[2*j+1] = u.w;
        float4 s = s4[j]; sre[2*j] = s.x; sim[2*j] = s.y; sre[2*j+1] = s.z; sim[2*j+1] = s.w;
    }
    float Dh = Dp[layer * H_ + hh];
    size_t base = ((size_t)b * L_ + c * LC) * H_ + hh;
    const float* xp = hin + base;
    float* yp = yout + base;
    #pragma unroll 1
    for (int t = 0; t < LC; t++) {
        float xv = xp[t * H_];
        float a0 = 0.f, a1 = 0.f, a2 = 0.f, a3 = 0.f;
        #pragma unroll
        for (int n = 0; n < N2_; n += 4) {
            STEP(n + 0, a0) STEP(n + 1, a1) STEP(n + 2, a2) STEP(n + 3, a3)
        }
        float v = fmaf(Dh, xv, (a0 + a1) + (a2 + a3));
        // tanh-approx gelu: v * sigmoid(2*0.79788456*(v + 0.044715 v^3))
        float g = 0.7978845608028654f * fmaf(0.044715f * v, v * v, v);
        float yv = v / (1.f + __expf(-2.f * g));
        yp[t * H_] = yv;
    }
}
#undef STEP

// ---------------------------------------------------------------------------
// fused: u = WoT^T@y + bo ; z = u[:256]*sigmoid(u[256:]) ; h = LN(z + h)*lnw+lnb
__global__ __launch_bounds__(256) void k_glu_ln(
    const float* __restrict__ y, float* __restrict__ h,
    const float* __restrict__ wot, const float* __restrict__ bo,
    const float* __restrict__ lnw, const float* __restrict__ lnb)
{
    __shared__ float As[16][36];      // k-major y tile (32 pos x 16 k)
    __shared__ float Bs[16 * 512];
    int m0 = blockIdx.x * 32;
    int tid = threadIdx.x;
    int tx = tid & 31, ty = tid >> 5;
    float acc[4][16];                 // [pos][j] j:0-3 nv0,4-7 nv1,8-11 gate0,12-15 gate1
    #pragma unroll
    for (int p = 0; p < 4; p++)
        #pragma unroll
        for (int j = 0; j < 16; j++) acc[p][j] = 0.f;
    const float4* wot4 = (const float4*)wot;
    float4* Bs4 = (float4*)Bs;
    for (int ks = 0; ks < 16; ks++) {
        int k0 = ks * 16;
        {
            int r = tid >> 3;
            int c2 = (tid & 7) * 2;
            float2 v = *(const float2*)(y + (size_t)(m0 + r) * H_ + k0 + c2);
            As[c2][r] = v.x; As[c2 + 1][r] = v.y;
        }
        #pragma unroll
        for (int it = 0; it < 8; it++) {
            int q = it * 256 + tid;
            Bs4[q] = wot4[(size_t)k0 * 128 + q];
        }
        __syncthreads();
        #pragma unroll 4
        for (int kk = 0; kk < 16; kk++) {
            float4 a = *(const float4*)&As[kk][ty * 4];
            const float4* brow = Bs4 + kk * 128;
            float4 b0 = brow[tx], b1 = brow[32 + tx], g0 = brow[64 + tx], g1 = brow[96 + tx];
            float av[4] = {a.x, a.y, a.z, a.w};
            float bv[16] = {b0.x, b0.y, b0.z, b0.w, b1.x, b1.y, b1.z, b1.w,
                            g0.x, g0.y, g0.z, g0.w, g1.x, g1.y, g1.z, g1.w};
            #pragma unroll
            for (int p = 0; p < 4; p++)
                #pragma unroll
                for (int j = 0; j < 16; j++)
                    acc[p][j] = fmaf(av[p], bv[j], acc[p][j]);
        }
        __syncthreads();
    }
    int nv0 = tx * 4, nv1 = 128 + tx * 4;
    float4 bv0 = *(const float4*)&bo[nv0];
    float4 bv1 = *(const float4*)&bo[nv1];
    float4 bg0 = *(const float4*)&bo[256 + nv0];
    float4 bg1 = *(const float4*)&bo[256 + nv1];
    float4 lw0 = *(const float4*)&lnw[nv0];
    float4 lw1 = *(const float4*)&lnw[nv1];
    float4 lb0 = *(const float4*)&lnb[nv0];
    float4 lb1 = *(const float4*)&lnb[nv1];
    float bov[8] = {bv0.x, bv0.y, bv0.z, bv0.w, bv1.x, bv1.y, bv1.z, bv1.w};
    float bog[8] = {bg0.x, bg0.y, bg0.z, bg0.w, bg1.x, bg1.y, bg1.z, bg1.w};
    float lwv[8] = {lw0.x, lw0.y, lw0.z, lw0.w, lw1.x, lw1.y, lw1.z, lw1.w};
    float lbv[8] = {lb0.x, lb0.y, lb0.z, lb0.w, lb1.x, lb1.y, lb1.z, lb1.w};
    float4* h4 = (float4*)h;
    #pragma unroll
    for (int p = 0; p < 4; p++) {
        size_t pos = m0 + ty * 4 + p;
        float4 h0 = h4[pos * 64 + tx];
        float4 h1 = h4[pos * 64 + 32 + tx];
        float hold[8] = {h0.x, h0.y, h0.z, h0.w, h1.x, h1.y, h1.z, h1.w};
        float hn[8];
        float s = 0.f, ss = 0.f;
        #pragma unroll
        for (int j = 0; j < 8; j++) {
            float uv = acc[p][j] + bov[j];
            float ug = acc[p][j + 8] + bog[j];
            float z = uv / (1.f + __expf(-ug));
            float v = z + hold[j];
            hn[j] = v; s += v; ss += v * v;
        }
        #pragma unroll
        for (int off = 16; off >= 1; off >>= 1) {
            s  += __shfl_xor(s, off);
            ss += __shfl_xor(ss, off);
        }
        float mu = s * (1.f / 256.f);
        float var = ss * (1.f / 256.f) - mu * mu;
        float rstd = rsqrtf(var + 1e-5f);
        #pragma unroll
        for (int j = 0; j < 8; j++)
            hn[j] = (hn[j] - mu) * rstd * lwv[j] + lbv[j];
        h4[pos * 64 + tx]      = make_float4(hn[0], hn[1], hn[2], hn[3]);
        h4[pos * 64 + 32 + tx] = make_float4(hn[4], hn[5], hn[6], hn[7]);
    }
}

// ---------------------------------------------------------------------------
__global__ __launch_bounds__(256) void k_decoder(const float* __restrict__ h,
    const float* __restrict__ out_W, const float* __restrict__ out_b,
    float* __restrict__ out)
{
    __shared__ float hs[16][260];
    __shared__ float wl[10][260];
    int p0 = blockIdx.x * 16;
    int tid = threadIdx.x;
    const float4* h4 = (const float4*)h;
    #pragma unroll
    for (int it = 0; it < 4; it++) {
        int q = it * 256 + tid;
        int r = q >> 6, k4 = q & 63;
        float4 v = h4[(size_t)(p0 + r) * 64 + k4];
        *(float4*)&hs[r][k4 * 4] = v;
    }
    for (int q = tid; q < 640; q += 256) {
        int r = q / 64, k4 = q % 64;
        *(float4*)&wl[r][k4 * 4] = ((const float4*)out_W)[q];
    }
    __syncthreads();
    int slot = tid & 15, pl = tid >> 4;
    if (slot < DOUT) {
        float a0 = 0.f, a1 = 0.f, a2 = 0.f, a3 = 0.f;
        #pragma unroll 8
        for (int k = 0; k < 256; k += 4) {
            a0 = fmaf(hs[pl][k + 0], wl[slot][k + 0], a0);
            a1 = fmaf(hs[pl][k + 1], wl[slot][k + 1], a1);
            a2 = fmaf(hs[pl][k + 2], wl[slot][k + 2], a2);
            a3 = fmaf(hs[pl][k + 3], wl[slot][k + 3], a3);
        }
        out[(size_t)(p0 + pl) * DOUT + slot] = (a0 + a1) + (a2 + a3) + out_b[slot];
    }
}

// ---------------------------------------------------------------------------
extern "C" void kernel_launch(void* const* d_in, const int* in_sizes, int n_in,
                              void* d_out, int out_size, void* d_ws, size_t ws_size,
                              hipStream_t stream)
{
    (void)in_sizes; (void)n_in; (void)out_size; (void)ws_size;
    const float* x        = (const float*)d_in[0];
    const float* enc_W    = (const float*)d_in[1];
    const float* enc_b    = (const float*)d_in[2];
    const float* log_dt   = (const float*)d_in[3];
    const float* log_A_re = (const float*)d_in[4];
    const float* A_im     = (const float*)d_in[5];
    const float* C_re     = (const float*)d_in[6];
    const float* C_im     = (const float*)d_in[7];
    const float* Dp       = (const float*)d_in[8];
    const float* Wo       = (const float*)d_in[9];
    const float* bo       = (const float*)d_in[10];
    const float* lnw      = (const float*)d_in[11];
    const float* lnb      = (const float*)d_in[12];
    const float* out_W    = (const float*)d_in[13];
    const float* out_b    = (const float*)d_in[14];
    float* ws = (float*)d_ws;
    float* h  = ws + OFF_H;
    float* y  = ws + OFF_Y;
    float* st = ws + OFF_ST;

    k_params<<<NL_ * H_ * N2_ / 256, 256, 0, stream>>>(log_dt, log_A_re, A_im, C_re, C_im, ws);
    dim3 tb(32, 8);
    k_transpose<<<dim3(DIN / 32, H_ / 32), tb, 0, stream>>>(enc_W, ws + OFF_EWT, H_, DIN);
    for (int i = 0; i < NL_; i++)
        k_transpose<<<dim3(H_ / 32, (2 * H_) / 32), tb, 0, stream>>>(
            Wo + (size_t)i * 2 * H_ * H_, ws + OFF_WOT + (size_t)i * 2 * H_ * H_, 2 * H_, H_);
    k_encoder<<<M_ / 32, 256, 0, stream>>>(x, ws + OFF_EWT, enc_b, h);
    for (int i = 0; i < NL_; i++) {
        k_chunkstate<<<B_ * CHK * (H_ / 8), 256, 0, stream>>>(h, ws, i, st);
        k_scan<<<B_ * H_ * N2_ / 256, 256, 0, stream>>>(ws, i, st);
        k_conv<<<B_ * CHK, 256, 0, stream>>>(h, ws, i, Dp, st, y);
        k_glu_ln<<<M_ / 32, 256, 0, stream>>>(y, h,
            ws + OFF_WOT + (size_t)i * 2 * H_ * H_, bo + (size_t)i * 2 * H_,
            lnw + (size_t)i * H_, lnb + (size_t)i * H_);
    }
    k_decoder<<<M_ / 16, 256, 0, stream>>>(h, out_W, out_b, (float*)d_out);
}

// Round 2
// 760.266 us; speedup vs baseline: 1.3392x; 1.3392x over previous
//
#include <hip/hip_runtime.h>
#include <hip/hip_bf16.h>

// ---------------------------------------------------------------------------
// S4D stack: encoder GEMM -> 4x[SSM scan conv + GELU -> GLU MFMA GEMM + LN] -> dec
// h stays fp32 (B*L, H); y and Wo are bf16 for the MFMA GEMM.
// Conv implemented as chunked linear recurrence (3 passes), not FFT.
// ---------------------------------------------------------------------------

constexpr int B_ = 4, L_ = 8192, DIN = 64, H_ = 256, N2_ = 32, NL_ = 4, DOUT = 10;
constexpr int LC = 64, CHK = L_ / LC;     // chunk len 64, 128 chunks
constexpr int M_ = B_ * L_;               // 32768 positions

// ws layout in float slots
constexpr size_t SZ_H    = (size_t)M_ * H_;            // 8.39M
constexpr size_t OFF_H   = 0;
constexpr size_t OFF_Y   = OFF_H + SZ_H;               // bf16 y: SZ_H/2 slots
constexpr size_t OFF_ST  = OFF_Y + SZ_H / 2;
constexpr size_t SZ_ST   = (size_t)B_ * CHK * H_ * N2_ * 2;
constexpr size_t SZ_P    = (size_t)NL_ * H_ * N2_ * 2;
constexpr size_t OFF_W   = OFF_ST + SZ_ST;
constexpr size_t OFF_CT  = OFF_W + SZ_P;
constexpr size_t OFF_WLC = OFF_CT + SZ_P;
constexpr size_t OFF_EWT = OFF_WLC + SZ_P;
constexpr size_t SZ_EWT  = (size_t)DIN * H_;
constexpr size_t OFF_WOB = OFF_EWT + SZ_EWT;           // bf16 Wo: NL*512*256 -> /2 slots

typedef short bf16x8 __attribute__((ext_vector_type(8)));
typedef float f32x4  __attribute__((ext_vector_type(4)));

// ---------------------------------------------------------------------------
// per-layer SSM parameters: w = exp(dt*A), Ct2 = 2*C*(w-1)/A, wLc = w^LC
__global__ __launch_bounds__(256) void k_params(
    const float* __restrict__ log_dt, const float* __restrict__ log_A_re,
    const float* __restrict__ A_im, const float* __restrict__ C_re,
    const float* __restrict__ C_im, float* __restrict__ ws)
{
    int idx = blockIdx.x * 256 + threadIdx.x;     // over NL*H*N2
    if (idx >= NL_ * H_ * N2_) return;
    int i  = idx / (H_ * N2_);
    int hh = (idx / N2_) % H_;
    float dt  = expf(log_dt[i * H_ + hh]);
    float Are = -expf(log_A_re[idx]);
    float Aim = A_im[idx];
    float zre = dt * Are, zim = dt * Aim;
    float er  = expf(zre);
    float wre = er * cosf(zim), wim = er * sinf(zim);
    float d   = Are * Are + Aim * Aim;
    float nre = wre - 1.f, nim = wim;
    float qre = (nre * Are + nim * Aim) / d;
    float qim = (nim * Are - nre * Aim) / d;
    float cr = C_re[idx], ci = C_im[idx];
    float ctre = cr * qre - ci * qim;
    float ctim = cr * qim + ci * qre;
    float er2 = expf(zre * (float)LC);
    float wlre = er2 * cosf(zim * (float)LC);
    float wlim = er2 * sinf(zim * (float)LC);
    ((float2*)(ws + OFF_W))[idx]   = make_float2(wre, wim);
    ((float2*)(ws + OFF_CT))[idx]  = make_float2(2.f * ctre, 2.f * ctim);
    ((float2*)(ws + OFF_WLC))[idx] = make_float2(wlre, wlim);
}

// ---------------------------------------------------------------------------
__global__ __launch_bounds__(256) void k_transpose(const float* __restrict__ src,
    float* __restrict__ dst, int R, int Cc)   // src R x Cc -> dst Cc x R
{
    __shared__ float t[32][33];
    int x = blockIdx.x * 32 + threadIdx.x;
    #pragma unroll
    for (int i = 0; i < 4; i++) {
        int yy = blockIdx.y * 32 + threadIdx.y + i * 8;
        if (x < Cc && yy < R) t[threadIdx.y + i * 8][threadIdx.x] = src[(size_t)yy * Cc + x];
    }
    __syncthreads();
    int xo = blockIdx.y * 32 + threadIdx.x;
    #pragma unroll
    for (int i = 0; i < 4; i++) {
        int yo = blockIdx.x * 32 + threadIdx.y + i * 8;
        if (xo < R && yo < Cc) dst[(size_t)yo * R + xo] = t[threadIdx.x][threadIdx.y + i * 8];
    }
}

// ---------------------------------------------------------------------------
// fp32 -> bf16 convert (Wo weights), 4 elements/thread
__global__ __launch_bounds__(256) void k_wcvt(const float* __restrict__ src,
    __hip_bfloat16* __restrict__ dst, int n4)
{
    int i = blockIdx.x * 256 + threadIdx.x;
    if (i >= n4) return;
    float4 v = ((const float4*)src)[i];
    union { __hip_bfloat16 b[4]; uint2 u; } o;
    o.b[0] = __float2bfloat16(v.x); o.b[1] = __float2bfloat16(v.y);
    o.b[2] = __float2bfloat16(v.z); o.b[3] = __float2bfloat16(v.w);
    ((uint2*)dst)[i] = o.u;
}

// ---------------------------------------------------------------------------
// encoder: h[M,256] = x[M,64] @ encWT[64,256] + enc_b
__global__ __launch_bounds__(256) void k_encoder(const float* __restrict__ x,
    const float* __restrict__ encWT, const float* __restrict__ enc_b,
    float* __restrict__ h)
{
    __shared__ float As[DIN][36];
    __shared__ float Bs[32][256];
    int m0 = blockIdx.x * 32;
    int tid = threadIdx.x;
    const float4* x4 = (const float4*)x;
    #pragma unroll
    for (int q = 0; q < 2; q++) {
        int f = tid * 2 + q;
        int row = f >> 4, kq = f & 15;
        float4 v = x4[(size_t)(m0 + row) * 16 + kq];
        As[kq * 4 + 0][row] = v.x; As[kq * 4 + 1][row] = v.y;
        As[kq * 4 + 2][row] = v.z; As[kq * 4 + 3][row] = v.w;
    }
    int tx = tid & 31, ty = tid >> 5;
    float acc[4][8];
    #pragma unroll
    for (int p = 0; p < 4; p++)
        #pragma unroll
        for (int j = 0; j < 8; j++) acc[p][j] = 0.f;
    const float4* w4 = (const float4*)encWT;
    for (int ks = 0; ks < 2; ks++) {
        __syncthreads();
        #pragma unroll
        for (int it = 0; it < 8; it++) {
            int q = it * 256 + tid;
            ((float4*)Bs)[q] = w4[ks * 2048 + q];
        }
        __syncthreads();
        #pragma unroll 8
        for (int kk = 0; kk < 32; kk++) {
            int k = ks * 32 + kk;
            float4 a  = *(const float4*)&As[k][ty * 4];
            float4 b0 = *(const float4*)&Bs[kk][tx * 4];
            float4 b1 = *(const float4*)&Bs[kk][128 + tx * 4];
            float av[4] = {a.x, a.y, a.z, a.w};
            float bv[8] = {b0.x, b0.y, b0.z, b0.w, b1.x, b1.y, b1.z, b1.w};
            #pragma unroll
            for (int p = 0; p < 4; p++)
                #pragma unroll
                for (int j = 0; j < 8; j++)
                    acc[p][j] = fmaf(av[p], bv[j], acc[p][j]);
        }
    }
    float4 eb0 = *(const float4*)&enc_b[tx * 4];
    float4 eb1 = *(const float4*)&enc_b[128 + tx * 4];
    float ebv[8] = {eb0.x, eb0.y, eb0.z, eb0.w, eb1.x, eb1.y, eb1.z, eb1.w};
    float4* h4 = (float4*)h;
    #pragma unroll
    for (int p = 0; p < 4; p++) {
        size_t pos = m0 + ty * 4 + p;
        float4 o0 = make_float4(acc[p][0] + ebv[0], acc[p][1] + ebv[1],
                                acc[p][2] + ebv[2], acc[p][3] + ebv[3]);
        float4 o1 = make_float4(acc[p][4] + ebv[4], acc[p][5] + ebv[5],
                                acc[p][6] + ebv[6], acc[p][7] + ebv[7]);
        h4[pos * 64 + tx]      = o0;
        h4[pos * 64 + 32 + tx] = o1;
    }
}

// ---------------------------------------------------------------------------
// pass1: per-chunk local final state (zero init). thread = (b,c,h,n)
__global__ __launch_bounds__(256) void k_chunkstate(const float* __restrict__ hin,
    const float* __restrict__ ws, int layer, float* __restrict__ st)
{
    int bid = blockIdx.x;
    int hg = bid & 31;
    int c  = (bid >> 5) & (CHK - 1);
    int b  = bid >> 12;
    int n  = threadIdx.x & 31;
    int hh = hg * 8 + (threadIdx.x >> 5);
    float2 w = ((const float2*)(ws + OFF_W))[(size_t)layer * H_ * N2_ + hh * N2_ + n];
    float sre = 0.f, sim = 0.f;
    const float* xp = hin + ((size_t)b * L_ + c * LC) * H_ + hh;
    #pragma unroll 4
    for (int t = 0; t < LC; t++) {
        float xv = xp[t * H_];
        float tre = fmaf(w.x, sre, xv);
        tre = fmaf(-w.y, sim, tre);
        float tim = fmaf(w.x, sim, w.y * sre);
        sre = tre; sim = tim;
    }
    ((float2*)st)[((size_t)(b * CHK + c) * H_ + hh) * N2_ + n] = make_float2(sre, sim);
}

// ---------------------------------------------------------------------------
// pass2: cross-chunk scan; st[c] becomes the INCOMING state of chunk c (in-place)
__global__ __launch_bounds__(256) void k_scan(const float* __restrict__ ws, int layer,
    float* __restrict__ st)
{
    int gid = blockIdx.x * 256 + threadIdx.x;   // B*H*N2 = 32768
    int b = gid >> 13;
    int r = gid & 8191;
    float2 wl = ((const float2*)(ws + OFF_WLC))[(size_t)layer * H_ * N2_ + r];
    float2* stp = (float2*)st;
    float cre = 0.f, cim = 0.f;
    for (int c = 0; c < CHK; c++) {
        size_t idx = (size_t)(b * CHK + c) * H_ * N2_ + r;
        float2 sl = stp[idx];
        stp[idx] = make_float2(cre, cim);
        float tre = fmaf(wl.x, cre, sl.x);
        tre = fmaf(-wl.y, cim, tre);
        float tim = fmaf(wl.x, cim, sl.y);
        tim = fmaf(wl.y, cre, tim);
        cre = tre; cim = tim;
    }
}

// ---------------------------------------------------------------------------
// pass3: replay with carries; y = gelu(conv + D*u) -> bf16. thread = channel
#define STEP(n, A) { \
    float tre = fmaf(wre[n], sre[n], xv); \
    tre = fmaf(-wim[n], sim[n], tre); \
    float tim = fmaf(wre[n], sim[n], wim[n] * sre[n]); \
    sre[n] = tre; sim[n] = tim; \
    A = fmaf(cre_[n], tre, A); \
    A = fmaf(-cim_[n], tim, A); }

__global__ __launch_bounds__(256) void k_conv(const float* __restrict__ hin,
    const float* __restrict__ ws, int layer, const float* __restrict__ Dp,
    const float* __restrict__ st, __hip_bfloat16* __restrict__ yout)
{
    int c = blockIdx.x & (CHK - 1);
    int b = blockIdx.x >> 7;
    int hh = threadIdx.x;
    float wre[N2_], wim[N2_], cre_[N2_], cim_[N2_], sre[N2_], sim[N2_];
    const float4* w4 = (const float4*)(ws + OFF_W  + ((size_t)layer * H_ * N2_ + hh * N2_) * 2);
    const float4* c4 = (const float4*)(ws + OFF_CT + ((size_t)layer * H_ * N2_ + hh * N2_) * 2);
    const float4* s4 = (const float4*)(st + ((size_t)(b * CHK + c) * H_ + hh) * N2_ * 2);
    #pragma unroll
    for (int j = 0; j < 16; j++) {
        float4 v = w4[j]; wre[2*j] = v.x; wim[2*j] = v.y; wre[2*j+1] = v.z; wim[2*j+1] = v.w;
        float4 u = c4[j]; cre_[2*j] = u.x; cim_[2*j] = u.y; cre_[2*j+1] = u.z; cim_[2*j+1] = u.w;
        float4 s = s4[j]; sre[2*j] = s.x; sim[2*j] = s.y; sre[2*j+1] = s.z; sim[2*j+1] = s.w;
    }
    float Dh = Dp[layer * H_ + hh];
    size_t base = ((size_t)b * L_ + c * LC) * H_ + hh;
    const float* xp = hin + base;
    __hip_bfloat16* yp = yout + base;
    #pragma unroll 1
    for (int t = 0; t < LC; t++) {
        float xv = xp[t * H_];
        float a0 = 0.f, a1 = 0.f, a2 = 0.f, a3 = 0.f;
        #pragma unroll
        for (int n = 0; n < N2_; n += 4) {
            STEP(n + 0, a0) STEP(n + 1, a1) STEP(n + 2, a2) STEP(n + 3, a3)
        }
        float v = fmaf(Dh, xv, (a0 + a1) + (a2 + a3));
        float g = 0.7978845608028654f * fmaf(0.044715f * v, v * v, v);
        float yv = v / (1.f + __expf(-2.f * g));
        yp[t * H_] = __float2bfloat16(yv);
    }
}
#undef STEP

// ---------------------------------------------------------------------------
// fused MFMA: u = y @ Wo^T + bo ; z = u[:256]*sigmoid(u[256:]) ; h = LN(z+h)
// block: 64 rows x full N=512. wave w owns value cols [w*64,w*64+64) + gates +256.
__global__ __launch_bounds__(256) void k_glu_mfma(
    const __hip_bfloat16* __restrict__ yb,   // [M,256] bf16 (k contiguous)
    float* __restrict__ h,                   // [M,256] f32 in/out
    const __hip_bfloat16* __restrict__ wob,  // [512,256] bf16 (n-major, k contiguous)
    const float* __restrict__ bo, const float* __restrict__ lnw,
    const float* __restrict__ lnb)
{
    int tid = threadIdx.x;
    int w   = tid >> 6;
    int l   = tid & 63;
    int l15 = l & 15, l4 = l >> 4;
    int m0  = blockIdx.x * 64;
    int nv  = w * 64;
    f32x4 accv[4][4], accg[4][4];
    #pragma unroll
    for (int mi = 0; mi < 4; mi++)
        #pragma unroll
        for (int nj = 0; nj < 4; nj++) { accv[mi][nj] = (f32x4)0.f; accg[mi][nj] = (f32x4)0.f; }

    #pragma unroll 1
    for (int ks = 0; ks < 8; ks++) {
        int k0 = ks * 32 + l4 * 8;
        bf16x8 a[4];
        #pragma unroll
        for (int mi = 0; mi < 4; mi++)
            a[mi] = *(const bf16x8*)(yb + (size_t)(m0 + mi * 16 + l15) * H_ + k0);
        #pragma unroll
        for (int nj = 0; nj < 4; nj++) {
            bf16x8 bv = *(const bf16x8*)(wob + (size_t)(nv + nj * 16 + l15) * H_ + k0);
            bf16x8 bg = *(const bf16x8*)(wob + (size_t)(256 + nv + nj * 16 + l15) * H_ + k0);
            #pragma unroll
            for (int mi = 0; mi < 4; mi++) {
                accv[mi][nj] = __builtin_amdgcn_mfma_f32_16x16x32_bf16(a[mi], bv, accv[mi][nj], 0, 0, 0);
                accg[mi][nj] = __builtin_amdgcn_mfma_f32_16x16x32_bf16(a[mi], bg, accg[mi][nj], 0, 0, 0);
            }
        }
    }

    float bov[4], bog[4], lw[4], lb[4];
    #pragma unroll
    for (int nj = 0; nj < 4; nj++) {
        int cn = nv + nj * 16 + l15;
        bov[nj] = bo[cn]; bog[nj] = bo[256 + cn];
        lw[nj] = lnw[cn]; lb[nj] = lnb[cn];
    }
    __shared__ float red[4][64][2];
    // GLU + residual; v kept in accv; per-row partial sums -> LDS
    #pragma unroll
    for (int mi = 0; mi < 4; mi++) {
        #pragma unroll
        for (int r = 0; r < 4; r++) {
            int lr = mi * 16 + l4 * 4 + r;
            size_t row = (size_t)(m0 + lr);
            float s = 0.f, ss = 0.f;
            #pragma unroll
            for (int nj = 0; nj < 4; nj++) {
                float uv = accv[mi][nj][r] + bov[nj];
                float ug = accg[mi][nj][r] + bog[nj];
                float z  = uv / (1.f + __expf(-ug));
                float v  = z + h[row * H_ + nv + nj * 16 + l15];
                accv[mi][nj][r] = v;
                s += v; ss += v * v;
            }
            #pragma unroll
            for (int off = 1; off < 16; off <<= 1) {
                s  += __shfl_xor(s, off);
                ss += __shfl_xor(ss, off);
            }
            if (l15 == 0) { red[w][lr][0] = s; red[w][lr][1] = ss; }
        }
    }
    __syncthreads();
    #pragma unroll
    for (int mi = 0; mi < 4; mi++) {
        #pragma unroll
        for (int r = 0; r < 4; r++) {
            int lr = mi * 16 + l4 * 4 + r;
            size_t row = (size_t)(m0 + lr);
            float s  = red[0][lr][0] + red[1][lr][0] + red[2][lr][0] + red[3][lr][0];
            float ss = red[0][lr][1] + red[1][lr][1] + red[2][lr][1] + red[3][lr][1];
            float mu = s * (1.f / 256.f);
            float var = ss * (1.f / 256.f) - mu * mu;
            float rstd = rsqrtf(var + 1e-5f);
            #pragma unroll
            for (int nj = 0; nj < 4; nj++)
                h[row * H_ + nv + nj * 16 + l15] =
                    (accv[mi][nj][r] - mu) * rstd * lw[nj] + lb[nj];
        }
    }
}

// ---------------------------------------------------------------------------
__global__ __launch_bounds__(256) void k_decoder(const float* __restrict__ h,
    const float* __restrict__ out_W, const float* __restrict__ out_b,
    float* __restrict__ out)
{
    __shared__ float hs[16][260];
    __shared__ float wl[10][260];
    int p0 = blockIdx.x * 16;
    int tid = threadIdx.x;
    const float4* h4 = (const float4*)h;
    #pragma unroll
    for (int it = 0; it < 4; it++) {
        int q = it * 256 + tid;
        int r = q >> 6, k4 = q & 63;
        float4 v = h4[(size_t)(p0 + r) * 64 + k4];
        *(float4*)&hs[r][k4 * 4] = v;
    }
    for (int q = tid; q < 640; q += 256) {
        int r = q / 64, k4 = q % 64;
        *(float4*)&wl[r][k4 * 4] = ((const float4*)out_W)[q];
    }
    __syncthreads();
    int slot = tid & 15, pl = tid >> 4;
    if (slot < DOUT) {
        float a0 = 0.f, a1 = 0.f, a2 = 0.f, a3 = 0.f;
        #pragma unroll 8
        for (int k = 0; k < 256; k += 4) {
            a0 = fmaf(hs[pl][k + 0], wl[slot][k + 0], a0);
            a1 = fmaf(hs[pl][k + 1], wl[slot][k + 1], a1);
            a2 = fmaf(hs[pl][k + 2], wl[slot][k + 2], a2);
            a3 = fmaf(hs[pl][k + 3], wl[slot][k + 3], a3);
        }
        out[(size_t)(p0 + pl) * DOUT + slot] = (a0 + a1) + (a2 + a3) + out_b[slot];
    }
}

// ---------------------------------------------------------------------------
extern "C" void kernel_launch(void* const* d_in, const int* in_sizes, int n_in,
                              void* d_out, int out_size, void* d_ws, size_t ws_size,
                              hipStream_t stream)
{
    (void)in_sizes; (void)n_in; (void)out_size; (void)ws_size;
    const float* x        = (const float*)d_in[0];
    const float* enc_W    = (const float*)d_in[1];
    const float* enc_b    = (const float*)d_in[2];
    const float* log_dt   = (const float*)d_in[3];
    const float* log_A_re = (const float*)d_in[4];
    const float* A_im     = (const float*)d_in[5];
    const float* C_re     = (const float*)d_in[6];
    const float* C_im     = (const float*)d_in[7];
    const float* Dp       = (const float*)d_in[8];
    const float* Wo       = (const float*)d_in[9];
    const float* bo       = (const float*)d_in[10];
    const float* lnw      = (const float*)d_in[11];
    const float* lnb      = (const float*)d_in[12];
    const float* out_W    = (const float*)d_in[13];
    const float* out_b    = (const float*)d_in[14];
    float* ws = (float*)d_ws;
    float* h  = ws + OFF_H;
    __hip_bfloat16* y = (__hip_bfloat16*)(ws + OFF_Y);
    float* st = ws + OFF_ST;
    __hip_bfloat16* wob = (__hip_bfloat16*)(ws + OFF_WOB);

    k_params<<<NL_ * H_ * N2_ / 256, 256, 0, stream>>>(log_dt, log_A_re, A_im, C_re, C_im, ws);
    dim3 tb(32, 8);
    k_transpose<<<dim3(DIN / 32, H_ / 32), tb, 0, stream>>>(enc_W, ws + OFF_EWT, H_, DIN);
    k_wcvt<<<(NL_ * 2 * H_ * H_ / 4 + 255) / 256, 256, 0, stream>>>(Wo, wob, NL_ * 2 * H_ * H_ / 4);
    k_encoder<<<M_ / 32, 256, 0, stream>>>(x, ws + OFF_EWT, enc_b, h);
    for (int i = 0; i < NL_; i++) {
        k_chunkstate<<<B_ * CHK * (H_ / 8), 256, 0, stream>>>(h, ws, i, st);
        k_scan<<<B_ * H_ * N2_ / 256, 256, 0, stream>>>(ws, i, st);
        k_conv<<<B_ * CHK, 256, 0, stream>>>(h, ws, i, Dp, st, y);
        k_glu_mfma<<<M_ / 64, 256, 0, stream>>>(y, h,
            wob + (size_t)i * 2 * H_ * H_, bo + (size_t)i * 2 * H_,
            lnw + (size_t)i * H_, lnb + (size_t)i * H_);
    }
    k_decoder<<<M_ / 16, 256, 0, stream>>>(h, out_W, out_b, (float*)d_out);
}